// Round 1
// baseline (227.870 us; speedup 1.0000x reference)
//
#include <hip/hip_runtime.h>

typedef __attribute__((ext_vector_type(8))) short short8;
typedef __attribute__((ext_vector_type(4))) float f32x4;

#define EPS 1e-6f
#define NB 2048

static __device__ __forceinline__ short f2bf(float f) {
    unsigned u = __float_as_uint(f);
    unsigned r = (u + 0x7FFFu + ((u >> 16) & 1u)) >> 16;
    return (short)(unsigned short)r;
}

// ---- prep: bf16 relation embeds (padded to 64 rows) + per-relation const ----
__global__ void prep_kernel(const float* __restrict__ re, short* __restrict__ re_bf,
                            float* __restrict__ re_c2, int R) {
    int tid = threadIdx.x;          // 256 threads, 1 block
    int r = tid >> 2, q = tid & 3;  // r in 0..63, q = quarter of the row
    float v[32];
    if (r < R) {
        const float* p = re + (size_t)r * 128 + q * 32;
#pragma unroll
        for (int j = 0; j < 32; ++j) v[j] = p[j];
    } else {
#pragma unroll
        for (int j = 0; j < 32; ++j) v[j] = 0.f;
    }
    float ssq = 0.f, sum = 0.f;
#pragma unroll
    for (int j = 0; j < 32; ++j) { ssq = fmaf(v[j], v[j], ssq); sum += v[j]; }
    ssq += __shfl_xor(ssq, 1); ssq += __shfl_xor(ssq, 2);
    sum += __shfl_xor(sum, 1); sum += __shfl_xor(sum, 2);
    short* o = re_bf + r * 128 + q * 32;
#pragma unroll
    for (int j = 0; j < 32; ++j) o[j] = f2bf(v[j]);
    if (q == 0) re_c2[r] = (r < R) ? (ssq - 2.f * EPS * sum) : -1e30f;
}

// ---- main: 16-row tiles per wave; MFMA 16x16x32 bf16 for the 64 dots ----
__global__ __launch_bounds__(256) void loss_main(
    const float* __restrict__ mo, const float* __restrict__ tg,
    const short* __restrict__ re_bf, const float* __restrict__ re_c2,
    float* __restrict__ partials, int nrows) {
    const int tid = threadIdx.x;
    const int lane = tid & 63;
    const int widx = tid >> 6;
    const int col16 = lane & 15;   // A-row index / C relation-col index
    const int kg = lane >> 4;      // k-group 0..3
    const int ko = kg * 8;

    // B fragments: 4 relation-tiles x 4 K-steps, kept in registers.
    short8 bfrag[4][4];
    float rc[4];
#pragma unroll
    for (int rt = 0; rt < 4; ++rt) {
#pragma unroll
        for (int s = 0; s < 4; ++s)
            bfrag[rt][s] = *reinterpret_cast<const short8*>(
                re_bf + (rt * 16 + col16) * 128 + s * 32 + ko);
        rc[rt] = re_c2[rt * 16 + col16];
    }

    float corr_acc = 0.f, inc_acc = 0.f;
    const int NT = nrows >> 4;       // 16-row tiles
    const int nw = gridDim.x * 4;
    for (int t = blockIdx.x * 4 + widx; t < NT; t += nw) {
        const size_t rowoff = (size_t)(t * 16 + col16) * 128 + ko;
        const float* rp = mo + rowoff;
        const float* tp = tg + rowoff;
        alignas(16) float x[32];
        alignas(16) float tv[32];
#pragma unroll
        for (int s = 0; s < 4; ++s) {
            *(f32x4*)(x + s * 8)     = *(const f32x4*)(rp + s * 32);
            *(f32x4*)(x + s * 8 + 4) = *(const f32x4*)(rp + s * 32 + 4);
        }
#pragma unroll
        for (int s = 0; s < 4; ++s) {
            *(f32x4*)(tv + s * 8)     = *(const f32x4*)(tp + s * 32);
            *(f32x4*)(tv + s * 8 + 4) = *(const f32x4*)(tp + s * 32 + 4);
        }
        // row stats (each row split across lanes {col16, col16+16, +32, +48})
        float ssq = 0.f, sum = 0.f;
#pragma unroll
        for (int j = 0; j < 32; ++j) { ssq = fmaf(x[j], x[j], ssq); sum += x[j]; }
        ssq += __shfl_xor(ssq, 16); ssq += __shfl_xor(ssq, 32);
        sum += __shfl_xor(sum, 16); sum += __shfl_xor(sum, 32);
        float rnorm = 1.0f / fmaxf(sqrtf(ssq), 1e-12f);
        float mo_sq = ssq * rnorm * rnorm;
        float mo_sum = sum * rnorm;

        // correct term: sum (mo - t + eps)^2 over the row
        float cs = 0.f;
#pragma unroll
        for (int j = 0; j < 32; ++j) {
            float d = fmaf(x[j], rnorm, EPS - tv[j]);
            cs = fmaf(d, d, cs);
        }
        cs += __shfl_xor(cs, 16); cs += __shfl_xor(cs, 32);
        if (lane < 16) corr_acc += sqrtf(cs);

        // A fragments (normalized, bf16)
        short8 afrag[4];
#pragma unroll
        for (int s = 0; s < 4; ++s)
#pragma unroll
            for (int j = 0; j < 8; ++j)
                afrag[s][j] = f2bf(x[s * 8 + j] * rnorm);

        // per-C-row constants: row m = kg*4 + reg lives on lane m (stats side)
        float mconst[4];
#pragma unroll
        for (int reg = 0; reg < 4; ++reg) {
            int src = kg * 4 + reg;
            float msq  = __shfl(mo_sq, src);
            float msum = __shfl(mo_sum, src);
            mconst[reg] = fmaf(2.f * EPS, msum, msq) + 128.f * EPS * EPS;
        }

        float vmax[4] = {-1e30f, -1e30f, -1e30f, -1e30f};
#pragma unroll
        for (int rt = 0; rt < 4; ++rt) {
            f32x4 acc = {0.f, 0.f, 0.f, 0.f};
#pragma unroll
            for (int s = 0; s < 4; ++s)
                acc = __builtin_amdgcn_mfma_f32_16x16x32_bf16(afrag[s], bfrag[rt][s], acc, 0, 0, 0);
#pragma unroll
            for (int reg = 0; reg < 4; ++reg) {
                float d2 = mconst[reg] + rc[rt] - 2.f * acc[reg];
                vmax[reg] = fmaxf(vmax[reg], d2);
            }
        }
        // max over the 16 relation-lanes (cols); rows are (kg*4+reg)
#pragma unroll
        for (int m = 1; m < 16; m <<= 1)
#pragma unroll
            for (int reg = 0; reg < 4; ++reg)
                vmax[reg] = fmaxf(vmax[reg], __shfl_xor(vmax[reg], m));
        if (col16 == 0) {
#pragma unroll
            for (int reg = 0; reg < 4; ++reg)
                inc_acc += sqrtf(fmaxf(vmax[reg], 0.f));
        }
    }

    __shared__ float redc[256];
    __shared__ float redi[256];
    redc[tid] = corr_acc; redi[tid] = inc_acc;
    __syncthreads();
    for (int s = 128; s > 0; s >>= 1) {
        if (tid < s) { redc[tid] += redc[tid + s]; redi[tid] += redi[tid + s]; }
        __syncthreads();
    }
    if (tid == 0) {
        partials[blockIdx.x * 2]     = redc[0];
        partials[blockIdx.x * 2 + 1] = redi[0];
    }
}

// ---- final: reduce block partials to the scalar loss ----
__global__ void final_kernel(const float* __restrict__ partials, float* __restrict__ out, int nb) {
    __shared__ float rc_[256];
    __shared__ float ri_[256];
    int tid = threadIdx.x;
    float c = 0.f, ic = 0.f;
    for (int i = tid; i < nb; i += 256) { c += partials[2 * i]; ic += partials[2 * i + 1]; }
    rc_[tid] = c; ri_[tid] = ic;
    __syncthreads();
    for (int s = 128; s > 0; s >>= 1) {
        if (tid < s) { rc_[tid] += rc_[tid + s]; ri_[tid] += ri_[tid + s]; }
        __syncthreads();
    }
    if (tid == 0) out[0] = c * 0.f + rc_[0] + 1e-4f * (1.f - ri_[0]);
}

extern "C" void kernel_launch(void* const* d_in, const int* in_sizes, int n_in,
                              void* d_out, int out_size, void* d_ws, size_t ws_size,
                              hipStream_t stream) {
    const float* mo = (const float*)d_in[0];
    const float* tg = (const float*)d_in[1];
    const float* re = (const float*)d_in[2];
    const int D = 128;
    const int nrows = in_sizes[0] / D;
    const int R = in_sizes[2] / D;

    char* ws = (char*)d_ws;
    short* re_bf   = (short*)ws;            // 64*128*2 = 16384 B
    float* re_c2   = (float*)(ws + 16384);  // 64*4 = 256 B
    float* partials = (float*)(ws + 16896); // NB*2*4 = 16384 B

    prep_kernel<<<1, 256, 0, stream>>>(re, re_bf, re_c2, R);
    loss_main<<<NB, 256, 0, stream>>>(mo, tg, re_bf, re_c2, partials, nrows);
    final_kernel<<<1, 256, 0, stream>>>(partials, (float*)d_out, NB);
}

// Round 2
// 188.223 us; speedup vs baseline: 1.2106x; 1.2106x over previous
//
#include <hip/hip_runtime.h>

typedef __attribute__((ext_vector_type(8))) short short8;
typedef __attribute__((ext_vector_type(4))) float f32x4;

#define EPS 1e-6f
#define NB 2048

static __device__ __forceinline__ short f2bf(float f) {
    unsigned u = __float_as_uint(f);
    unsigned r = (u + 0x7FFFu + ((u >> 16) & 1u)) >> 16;
    return (short)(unsigned short)r;
}

// ---- prep: bf16 relation embeds (padded to 64 rows) + per-relation const ----
__global__ void prep_kernel(const float* __restrict__ re, short* __restrict__ re_bf,
                            float* __restrict__ re_c2, int R) {
    int tid = threadIdx.x;          // 256 threads, 1 block
    int r = tid >> 2, q = tid & 3;  // r in 0..63, q = quarter of the row
    float v[32];
    if (r < R) {
        const float* p = re + (size_t)r * 128 + q * 32;
#pragma unroll
        for (int j = 0; j < 32; ++j) v[j] = p[j];
    } else {
#pragma unroll
        for (int j = 0; j < 32; ++j) v[j] = 0.f;
    }
    float ssq = 0.f, sum = 0.f;
#pragma unroll
    for (int j = 0; j < 32; ++j) { ssq = fmaf(v[j], v[j], ssq); sum += v[j]; }
    ssq += __shfl_xor(ssq, 1); ssq += __shfl_xor(ssq, 2);
    sum += __shfl_xor(sum, 1); sum += __shfl_xor(sum, 2);
    short* o = re_bf + r * 128 + q * 32;
#pragma unroll
    for (int j = 0; j < 32; ++j) o[j] = f2bf(v[j]);
    if (q == 0) re_c2[r] = (r < R) ? (ssq - 2.f * EPS * sum) : -1e30f;
}

// ---- main: 16-row tiles/wave; MFMA(relations, mo) so epilogue is lane-local ----
__global__ __launch_bounds__(256) void loss_main(
    const float* __restrict__ mo, const float* __restrict__ tg,
    const short* __restrict__ re_bf, const float* __restrict__ re_c2,
    float* __restrict__ partials, int nrows) {
    const int tid = threadIdx.x;
    const int lane = tid & 63;
    const int widx = tid >> 6;
    const int col16 = lane & 15;   // mo-row within tile (A-col side) / C col
    const int kg = lane >> 4;      // k-group 0..3
    const int ko = kg * 8;

    // Relation A-fragments in LDS, shared by all 4 waves.
    // layout [frag = rt*4+s][lane] of short8 -> ds_read_b128 at 16B/lane stride.
    __shared__ short8 bf_lds[16][64];
    if (widx == 0) {
#pragma unroll
        for (int rt = 0; rt < 4; ++rt)
#pragma unroll
            for (int s = 0; s < 4; ++s)
                bf_lds[rt * 4 + s][lane] = *reinterpret_cast<const short8*>(
                    re_bf + (rt * 16 + col16) * 128 + s * 32 + ko);
    }
    // per-lane relation constants: relation = rt*16 + kg*4 + reg  (C row ids)
    float rc[4][4];
#pragma unroll
    for (int rt = 0; rt < 4; ++rt)
#pragma unroll
        for (int reg = 0; reg < 4; ++reg)
            rc[rt][reg] = re_c2[rt * 16 + kg * 4 + reg];
    __syncthreads();

    float corr_acc = 0.f, inc_acc = 0.f;
    const int NT = nrows >> 4;       // 16-row tiles
    const int nw = gridDim.x * 4;
    int t = blockIdx.x * 4 + widx;

    if (t < NT) {
        alignas(16) float x[32];

        // prologue: load x(t0)
        {
            const float* rp = mo + ((size_t)(t * 16 + col16) * 128 + ko);
#pragma unroll
            for (int s = 0; s < 4; ++s) {
                *(f32x4*)(x + s * 8)     = *(const f32x4*)(rp + s * 32);
                *(f32x4*)(x + s * 8 + 4) = *(const f32x4*)(rp + s * 32 + 4);
            }
        }

        while (t < NT) {
            // issue target loads for this tile (consumed below, after ssq/sum)
            alignas(16) float tv[32];
            {
                const float* tp = tg + ((size_t)(t * 16 + col16) * 128 + ko);
#pragma unroll
                for (int s = 0; s < 4; ++s) {
                    *(f32x4*)(tv + s * 8)     = *(const f32x4*)(tp + s * 32);
                    *(f32x4*)(tv + s * 8 + 4) = *(const f32x4*)(tp + s * 32 + 4);
                }
            }

            // mo row stats (overlaps tv arrival)
            float ssq = 0.f, sum = 0.f;
#pragma unroll
            for (int j = 0; j < 32; ++j) { ssq = fmaf(x[j], x[j], ssq); sum += x[j]; }
            // target-coupled stats
            float xt = 0.f, tsq = 0.f, tsum = 0.f;
#pragma unroll
            for (int j = 0; j < 32; ++j) {
                xt  = fmaf(x[j], tv[j], xt);
                tsq = fmaf(tv[j], tv[j], tsq);
                tsum += tv[j];
            }
            // reduce the 5 stats across the 4 k-group lanes of this row
            ssq  += __shfl_xor(ssq, 16);  ssq  += __shfl_xor(ssq, 32);
            sum  += __shfl_xor(sum, 16);  sum  += __shfl_xor(sum, 32);
            xt   += __shfl_xor(xt, 16);   xt   += __shfl_xor(xt, 32);
            tsq  += __shfl_xor(tsq, 16);  tsq  += __shfl_xor(tsq, 32);
            tsum += __shfl_xor(tsum, 16); tsum += __shfl_xor(tsum, 32);

            float rnorm  = 1.0f / fmaxf(sqrtf(ssq), 1e-12f);
            float mo_sq  = ssq * rnorm * rnorm;
            float mo_sum = sum * rnorm;
            float mconst = fmaf(2.f * EPS, mo_sum, mo_sq) + 128.f * EPS * EPS;

            // correct term via expansion: ||m - t + eps||^2
            float cs = mconst + tsq - 2.f * EPS * tsum - 2.f * rnorm * xt;
            if (kg == 0) corr_acc += sqrtf(fmaxf(cs, 0.f));

            // pack normalized mo into B-fragment (lane holds row col16, k = ko+s*32..)
            short8 afrag[4];
#pragma unroll
            for (int s = 0; s < 4; ++s)
#pragma unroll
                for (int j = 0; j < 8; ++j)
                    afrag[s][j] = f2bf(x[s * 8 + j] * rnorm);

            // prefetch next tile's mo into x (consumed next iteration)
            int t2 = t + nw;
            if (t2 < NT) {
                const float* rp = mo + ((size_t)(t2 * 16 + col16) * 128 + ko);
#pragma unroll
                for (int s = 0; s < 4; ++s) {
                    *(f32x4*)(x + s * 8)     = *(const f32x4*)(rp + s * 32);
                    *(f32x4*)(x + s * 8 + 4) = *(const f32x4*)(rp + s * 32 + 4);
                }
            }

            // MFMA: A = relations (row = relation), B = mo (col = mo row)
            // C[relation][mo_row]: lane col16 = mo row, reg row = rt*16+kg*4+reg
            float vmax = -1e30f;
#pragma unroll
            for (int rt = 0; rt < 4; ++rt) {
                f32x4 acc = {0.f, 0.f, 0.f, 0.f};
#pragma unroll
                for (int s = 0; s < 4; ++s)
                    acc = __builtin_amdgcn_mfma_f32_16x16x32_bf16(
                        bf_lds[rt * 4 + s][lane], afrag[s], acc, 0, 0, 0);
#pragma unroll
                for (int reg = 0; reg < 4; ++reg) {
                    float d2 = mconst + rc[rt][reg] - 2.f * acc[reg];
                    vmax = fmaxf(vmax, d2);
                }
            }
            // max over the 4 kg groups (each covered 16 of the 64 relations)
            vmax = fmaxf(vmax, __shfl_xor(vmax, 16));
            vmax = fmaxf(vmax, __shfl_xor(vmax, 32));
            if (kg == 0) inc_acc += sqrtf(fmaxf(vmax, 0.f));

            t = t2;
        }
    }

    __shared__ float redc[256];
    __shared__ float redi[256];
    redc[tid] = corr_acc; redi[tid] = inc_acc;
    __syncthreads();
    for (int s = 128; s > 0; s >>= 1) {
        if (tid < s) { redc[tid] += redc[tid + s]; redi[tid] += redi[tid + s]; }
        __syncthreads();
    }
    if (tid == 0) {
        partials[blockIdx.x * 2]     = redc[0];
        partials[blockIdx.x * 2 + 1] = redi[0];
    }
}

// ---- final: reduce block partials to the scalar loss ----
__global__ void final_kernel(const float* __restrict__ partials, float* __restrict__ out, int nb) {
    __shared__ float rc_[256];
    __shared__ float ri_[256];
    int tid = threadIdx.x;
    float c = 0.f, ic = 0.f;
    for (int i = tid; i < nb; i += 256) { c += partials[2 * i]; ic += partials[2 * i + 1]; }
    rc_[tid] = c; ri_[tid] = ic;
    __syncthreads();
    for (int s = 128; s > 0; s >>= 1) {
        if (tid < s) { rc_[tid] += rc_[tid + s]; ri_[tid] += ri_[tid + s]; }
        __syncthreads();
    }
    if (tid == 0) out[0] = rc_[0] + 1e-4f * (1.f - ri_[0]);
}

extern "C" void kernel_launch(void* const* d_in, const int* in_sizes, int n_in,
                              void* d_out, int out_size, void* d_ws, size_t ws_size,
                              hipStream_t stream) {
    const float* mo = (const float*)d_in[0];
    const float* tg = (const float*)d_in[1];
    const float* re = (const float*)d_in[2];
    const int D = 128;
    const int nrows = in_sizes[0] / D;
    const int R = in_sizes[2] / D;

    char* ws = (char*)d_ws;
    short* re_bf    = (short*)ws;            // 64*128*2 = 16384 B
    float* re_c2    = (float*)(ws + 16384);  // 64*4 = 256 B
    float* partials = (float*)(ws + 16896);  // NB*2*4 = 16384 B

    prep_kernel<<<1, 256, 0, stream>>>(re, re_bf, re_c2, R);
    loss_main<<<NB, 256, 0, stream>>>(mo, tg, re_bf, re_c2, partials, nrows);
    final_kernel<<<1, 256, 0, stream>>>(partials, (float*)d_out, NB);
}